// Round 3
// baseline (293.439 us; speedup 1.0000x reference)
//
#include <hip/hip_runtime.h>

#define D256 256
#define TOTROWS 65536   // B*A*I = 4*32*512
#define BM 32
#define LDW 264         // padded row stride in u16 (528 B = 33 x 16B chunks)
#define NBLK (TOTROWS / BM)   // 2048
#define NT 256                // 4 waves; each owns 64 output cols (nb=2)

typedef unsigned short u16;
typedef unsigned int u32;
typedef __attribute__((ext_vector_type(8))) short bf16x8;
typedef __attribute__((ext_vector_type(16))) float f32x16;

__device__ __forceinline__ float b2f(u16 u) {
  union { u32 i; float f; } v; v.i = ((u32)u) << 16; return v.f;
}
__device__ __forceinline__ u16 f2b(float f) {
  union { float f; u32 i; } v; v.f = f;
  return (u16)((v.i + 0x7fffu + ((v.i >> 16) & 1u)) >> 16);  // RNE
}

// attn1 -> Wb[0] (row-major [j][k]), attn2 -> Wb[1]
__global__ void copy_convert(const float* __restrict__ a1,
                             const float* __restrict__ a2,
                             u16* __restrict__ out) {
  const int m = blockIdx.y;
  const float* src = m ? a2 : a1;
  const int idx = blockIdx.x * 256 + threadIdx.x;
  out[m * 65536 + idx] = f2b(src[idx]);
}

// W1 -> Wb[2] transposed ([n][j] = W1[j][n]), W2 -> Wb[3]
__global__ void transpose_convert(const float* __restrict__ W1,
                                  const float* __restrict__ W2,
                                  u16* __restrict__ out) {
  __shared__ float tile[32][33];
  const int m = blockIdx.z;
  const float* src = m ? W2 : W1;
  const int bx = blockIdx.x, by = blockIdx.y;
  const int tx = threadIdx.x, ty = threadIdx.y;
#pragma unroll
  for (int i = ty; i < 32; i += 8)
    tile[i][tx] = src[(by * 32 + i) * 256 + bx * 32 + tx];
  __syncthreads();
#pragma unroll
  for (int i = ty; i < 32; i += 8)
    out[m * 65536 + (bx * 32 + i) * 256 + by * 32 + tx] = f2b(tile[tx][i]);
}

// split-reduce: v[16] per-lane partials (rows (r&3)+8*(r>>2)+4*lh, col = base+l31)
// -> full 32-lane column sums, accumulated into sp[row]. 31 shfls total.
__device__ __forceinline__ void reduce_accum(float v[16], float* sp,
                                             int l31, int lh) {
#pragma unroll
  for (int r = 0; r < 8; r++) {
    float a = v[r]     + __shfl_xor(v[r],     1, 32);
    float b = v[r + 8] + __shfl_xor(v[r + 8], 1, 32);
    v[r] = (l31 & 1) ? b : a;
  }
#pragma unroll
  for (int r = 0; r < 4; r++) {
    float a = v[r]     + __shfl_xor(v[r],     2, 32);
    float b = v[r + 4] + __shfl_xor(v[r + 4], 2, 32);
    v[r] = (l31 & 2) ? b : a;
  }
#pragma unroll
  for (int r = 0; r < 2; r++) {
    float a = v[r]     + __shfl_xor(v[r],     4, 32);
    float b = v[r + 2] + __shfl_xor(v[r + 2], 4, 32);
    v[r] = (l31 & 4) ? b : a;
  }
  {
    float a = v[0] + __shfl_xor(v[0], 8, 32);
    float b = v[1] + __shfl_xor(v[1], 8, 32);
    v[0] = (l31 & 8) ? b : a;
  }
  v[0] += __shfl_xor(v[0], 16, 32);
  if (l31 < 16) {
    // value index i = 8*p0 + 4*p1 + 2*p2 + p3 from lane bits
    const int i = ((l31 & 1) << 3) | ((l31 & 2) << 1) | ((l31 & 4) >> 1) |
                  ((l31 & 8) >> 3);
    const int row = (i & 3) + 8 * (i >> 2) + 4 * lh;
    atomicAdd(&sp[row], v[0]);
  }
}

__global__ __launch_bounds__(NT, 4)
void fused(const float* __restrict__ X0g, const float* __restrict__ X1g,
           const u16* __restrict__ Wb, float* __restrict__ outg) {
  __shared__ u16 lX0[BM][LDW];   // 16.9 KB
  __shared__ u16 lX1[BM][LDW];   // 16.9 KB
  __shared__ float sp0[BM], sp1[BM], sc0[BM], sc1[BM];

  const int t = threadIdx.x;
  const int row0 = blockIdx.x * BM;

  if (t < BM) { sp0[t] = 0.f; sp1[t] = 0.f; }

  // ---- stage: fp32 global -> bf16 LDS (2048 float4 per tile, 8 iters) ----
  {
    const float4* g0 = (const float4*)(X0g + (size_t)row0 * D256);
    const float4* g1 = (const float4*)(X1g + (size_t)row0 * D256);
    ushort4* s0 = (ushort4*)&lX0[0][0];   // row stride = 66 ushort4
    ushort4* s1 = (ushort4*)&lX1[0][0];
#pragma unroll
    for (int i = 0; i < 8; i++) {
      const int e = i * NT + t;         // 64 float4 per row
      const int row = e >> 6;
      const int col = e & 63;
      float4 a = g0[e];
      float4 b = g1[e];
      ushort4 pa, pb;
      pa.x = f2b(a.x); pa.y = f2b(a.y); pa.z = f2b(a.z); pa.w = f2b(a.w);
      pb.x = f2b(b.x); pb.y = f2b(b.y); pb.z = f2b(b.z); pb.w = f2b(b.w);
      s0[row * 66 + col] = pa;
      s1[row * 66 + col] = pb;
    }
  }
  __syncthreads();

  const int ln  = t & 63;
  const int wv  = t >> 6;      // wave 0..3, owns 64 output cols
  const int l31 = ln & 31;
  const int lh  = ln >> 5;
  const int cb0  = wv * 64;
  const int col0 = cb0 + l31;        // nb=0 column
  const int col1 = cb0 + 32 + l31;   // nb=1 column

  // ---- pass 1: gate scores via MFMA, products, split-reduce ----
  {
    f32x16 G0[2], G1[2];
#pragma unroll
    for (int nb = 0; nb < 2; nb++)
#pragma unroll
      for (int i = 0; i < 16; i++) { G0[nb][i] = 0.f; G1[nb][i] = 0.f; }

    const u16* wa1_0 = Wb + col0 * 256 + lh * 8;
    const u16* wa1_1 = Wb + col1 * 256 + lh * 8;
    const u16* wa2_0 = Wb + 65536 + col0 * 256 + lh * 8;
    const u16* wa2_1 = Wb + 65536 + col1 * 256 + lh * 8;
#pragma unroll 4
    for (int k = 0; k < 16; k++) {
      bf16x8 af0 = *(const bf16x8*)(&lX0[l31][k * 16 + lh * 8]);
      bf16x8 af1 = *(const bf16x8*)(&lX1[l31][k * 16 + lh * 8]);
      G0[0] = __builtin_amdgcn_mfma_f32_32x32x16_bf16(
          af0, *(const bf16x8*)(wa1_0 + k * 16), G0[0], 0, 0, 0);
      G0[1] = __builtin_amdgcn_mfma_f32_32x32x16_bf16(
          af0, *(const bf16x8*)(wa1_1 + k * 16), G0[1], 0, 0, 0);
      G1[0] = __builtin_amdgcn_mfma_f32_32x32x16_bf16(
          af1, *(const bf16x8*)(wa2_0 + k * 16), G1[0], 0, 0, 0);
      G1[1] = __builtin_amdgcn_mfma_f32_32x32x16_bf16(
          af1, *(const bf16x8*)(wa2_1 + k * 16), G1[1], 0, 0, 0);
    }

    float v[16];
#pragma unroll
    for (int r = 0; r < 16; r++) {   // gate0: Z0 = X0@A1^T, other = X1
      const int row = (r & 3) + 8 * (r >> 2) + 4 * lh;
      v[r] = G0[0][r] * b2f(lX1[row][col0]) + G0[1][r] * b2f(lX1[row][col1]);
    }
    reduce_accum(v, sp0, l31, lh);
#pragma unroll
    for (int r = 0; r < 16; r++) {   // gate1: Z1 = X1@A2^T, other = X0
      const int row = (r & 3) + 8 * (r >> 2) + 4 * lh;
      v[r] = G1[0][r] * b2f(lX0[row][col0]) + G1[1][r] * b2f(lX0[row][col1]);
    }
    reduce_accum(v, sp1, l31, lh);
  }
  __syncthreads();

  if (t < BM) {
    sc0[t] = 1.f + 1.f / (1.f + __expf(-sp0[t]));
  } else if (t < 2 * BM) {
    sc1[t - BM] = 1.f + 1.f / (1.f + __expf(-sp1[t - BM]));
  }
  __syncthreads();

  // ---- pass 2: projections, scale in epilogue ----
  {
    f32x16 P0[2], P1[2];
#pragma unroll
    for (int nb = 0; nb < 2; nb++)
#pragma unroll
      for (int i = 0; i < 16; i++) { P0[nb][i] = 0.f; P1[nb][i] = 0.f; }

    const u16* w1_0 = Wb + 2 * 65536 + col0 * 256 + lh * 8;
    const u16* w1_1 = Wb + 2 * 65536 + col1 * 256 + lh * 8;
    const u16* w2_0 = Wb + 3 * 65536 + col0 * 256 + lh * 8;
    const u16* w2_1 = Wb + 3 * 65536 + col1 * 256 + lh * 8;
#pragma unroll 4
    for (int k = 0; k < 16; k++) {
      bf16x8 af0 = *(const bf16x8*)(&lX0[l31][k * 16 + lh * 8]);
      bf16x8 af1 = *(const bf16x8*)(&lX1[l31][k * 16 + lh * 8]);
      P0[0] = __builtin_amdgcn_mfma_f32_32x32x16_bf16(
          af0, *(const bf16x8*)(w1_0 + k * 16), P0[0], 0, 0, 0);
      P0[1] = __builtin_amdgcn_mfma_f32_32x32x16_bf16(
          af0, *(const bf16x8*)(w1_1 + k * 16), P0[1], 0, 0, 0);
      P1[0] = __builtin_amdgcn_mfma_f32_32x32x16_bf16(
          af1, *(const bf16x8*)(w2_0 + k * 16), P1[0], 0, 0, 0);
      P1[1] = __builtin_amdgcn_mfma_f32_32x32x16_bf16(
          af1, *(const bf16x8*)(w2_1 + k * 16), P1[1], 0, 0, 0);
    }

    float* opb = outg + (size_t)row0 * 256 + cb0;
#pragma unroll
    for (int q = 0; q < 4; q++) {
      float s0a[4], s1a[4];
      *(float4*)s0a = *(const float4*)&sc0[8 * q + 4 * lh];
      *(float4*)s1a = *(const float4*)&sc1[8 * q + 4 * lh];
#pragma unroll
      for (int j = 0; j < 4; j++) {
        const int r = q * 4 + j;
        const int row = j + 8 * q + 4 * lh;
        opb[row * 256 + l31]      = s0a[j] * P0[0][r] + s1a[j] * P1[0][r];
        opb[row * 256 + 32 + l31] = s0a[j] * P0[1][r] + s1a[j] * P1[1][r];
      }
    }
  }
}

extern "C" void kernel_launch(void* const* d_in, const int* in_sizes, int n_in,
                              void* d_out, int out_size, void* d_ws, size_t ws_size,
                              hipStream_t stream) {
  const float* i0 = (const float*)d_in[0];
  const float* i1 = (const float*)d_in[1];
  const float* W1 = (const float*)d_in[2];
  const float* W2 = (const float*)d_in[3];
  const float* a1 = (const float*)d_in[4];
  const float* a2 = (const float*)d_in[5];
  u16* Wb = (u16*)d_ws;   // 4 x 256x256 bf16 = 512 KB

  copy_convert<<<dim3(256, 2), 256, 0, stream>>>(a1, a2, Wb);
  transpose_convert<<<dim3(8, 8, 2), dim3(32, 8), 0, stream>>>(W1, W2, Wb + 2 * 65536);
  fused<<<NBLK, NT, 0, stream>>>(i0, i1, Wb, (float*)d_out);
}

// Round 4
// 211.457 us; speedup vs baseline: 1.3877x; 1.3877x over previous
//
#include <hip/hip_runtime.h>

#define D256 256
#define TOTROWS 65536   // B*A*I = 4*32*512
#define BM 32
#define LDW 264         // padded LDS row stride in u16 (528 B): 0 bank conflicts (r2)
#define NBLK (TOTROWS / BM)   // 2048
#define NT 512                // 8 waves; wave wv owns 32-col panel wv

typedef unsigned short u16;
typedef unsigned int u32;
typedef __attribute__((ext_vector_type(8))) short bf16x8;
typedef __attribute__((ext_vector_type(16))) float f32x16;

__device__ __forceinline__ float b2f(u16 u) {
  union { u32 i; float f; } v; v.i = ((u32)u) << 16; return v.f;
}
__device__ __forceinline__ u16 f2b(float f) {
  union { float f; u32 i; } v; v.f = f;
  return (u16)((v.i + 0x7fffu + ((v.i >> 16) & 1u)) >> 16);  // RNE
}

// Build weight fragments in MFMA B-operand lane order, bf16:
//   Wf[m][p][k][ln] (16B chunk) = Brow[m][col = p*32 + (ln&31)][k*16 + (ln>>5)*8 ..+8]
// where Brow[0]=attn1, Brow[1]=attn2 (row-major [n][k]),
//       Brow[2][n][j]=W1[j][n], Brow[3][n][j]=W2[j][n].
// A wave's B-frag load for (m,p,k) is then 64 lanes x 16B fully contiguous (1KB).
__global__ void build_wfrag(const float* __restrict__ a1,
                            const float* __restrict__ a2,
                            const float* __restrict__ W1,
                            const float* __restrict__ W2,
                            u16* __restrict__ Wf) {
  const int m = blockIdx.y;
  const int idx = blockIdx.x * 256 + threadIdx.x;   // 0..8191 per matrix
  int col, c;
  const float* src;
  if (m < 2) {            // attn: read row-major, coalesced over chunk id
    col = idx >> 5; c = idx & 31; src = m ? a2 : a1;
  } else {                // proj: read col-major (transpose), coalesced over col
    col = idx & 255; c = idx >> 8; src = (m == 3) ? W2 : W1;
  }
  const int kk0 = c * 8;
  const int p = col >> 5, l31 = col & 31, k = c >> 1, lh = c & 1;
  const int ln = lh * 32 + l31;
  u16* dst = Wf + m * 65536 + ((p * 16 + k) * 64 + ln) * 8;
  u16 v[8];
  if (m < 2) {
#pragma unroll
    for (int j = 0; j < 8; j++) v[j] = f2b(src[col * 256 + kk0 + j]);
  } else {
#pragma unroll
    for (int j = 0; j < 8; j++) v[j] = f2b(src[(kk0 + j) * 256 + col]);
  }
  ushort4 lo, hi;
  lo.x = v[0]; lo.y = v[1]; lo.z = v[2]; lo.w = v[3];
  hi.x = v[4]; hi.y = v[5]; hi.z = v[6]; hi.w = v[7];
  ((ushort4*)dst)[0] = lo;
  ((ushort4*)dst)[1] = hi;
}

// split-reduce: v[16] per-lane partials (rows (r&3)+8*(r>>2)+4*lh, col = base+l31)
// -> 32-lane column sums accumulated into sp[row]. 31 shfls. (verified r3)
__device__ __forceinline__ void reduce_accum(float v[16], float* sp,
                                             int l31, int lh) {
#pragma unroll
  for (int r = 0; r < 8; r++) {
    float a = v[r]     + __shfl_xor(v[r],     1, 32);
    float b = v[r + 8] + __shfl_xor(v[r + 8], 1, 32);
    v[r] = (l31 & 1) ? b : a;
  }
#pragma unroll
  for (int r = 0; r < 4; r++) {
    float a = v[r]     + __shfl_xor(v[r],     2, 32);
    float b = v[r + 4] + __shfl_xor(v[r + 4], 2, 32);
    v[r] = (l31 & 2) ? b : a;
  }
#pragma unroll
  for (int r = 0; r < 2; r++) {
    float a = v[r]     + __shfl_xor(v[r],     4, 32);
    float b = v[r + 2] + __shfl_xor(v[r + 2], 4, 32);
    v[r] = (l31 & 4) ? b : a;
  }
  {
    float a = v[0] + __shfl_xor(v[0], 8, 32);
    float b = v[1] + __shfl_xor(v[1], 8, 32);
    v[0] = (l31 & 8) ? b : a;
  }
  v[0] += __shfl_xor(v[0], 16, 32);
  if (l31 < 16) {
    const int i = ((l31 & 1) << 3) | ((l31 & 2) << 1) | ((l31 & 4) >> 1) |
                  ((l31 & 8) >> 3);
    const int row = (i & 3) + 8 * (i >> 2) + 4 * lh;
    atomicAdd(&sp[row], v[0]);
  }
}

__global__ __launch_bounds__(NT, 4)
void fused(const float* __restrict__ X0g, const float* __restrict__ X1g,
           const u16* __restrict__ Wf, float* __restrict__ outg) {
  __shared__ u16 lX0[BM][LDW];   // 16.9 KB
  __shared__ u16 lX1[BM][LDW];   // 16.9 KB -> 4 blocks/CU
  __shared__ float sp0[BM], sp1[BM], sc0[BM], sc1[BM];

  const int t = threadIdx.x;
  const int row0 = blockIdx.x * BM;

  if (t < BM) { sp0[t] = 0.f; sp1[t] = 0.f; }

  // ---- stage: fp32 global -> bf16 LDS (2048 float4/tensor, 4 iters) ----
  {
    const float4* g0 = (const float4*)(X0g + (size_t)row0 * D256);
    const float4* g1 = (const float4*)(X1g + (size_t)row0 * D256);
    ushort4* s0 = (ushort4*)&lX0[0][0];   // row stride = 66 ushort4
    ushort4* s1 = (ushort4*)&lX1[0][0];
#pragma unroll
    for (int i = 0; i < 4; i++) {
      const int e = i * NT + t;         // 64 float4 per row
      const int row = e >> 6;
      const int col = e & 63;
      float4 a = g0[e];
      float4 b = g1[e];
      ushort4 pa, pb;
      pa.x = f2b(a.x); pa.y = f2b(a.y); pa.z = f2b(a.z); pa.w = f2b(a.w);
      pb.x = f2b(b.x); pb.y = f2b(b.y); pb.z = f2b(b.z); pb.w = f2b(b.w);
      s0[row * 66 + col] = pa;
      s1[row * 66 + col] = pb;
    }
  }
  __syncthreads();

  const int ln  = t & 63;
  const int wv  = t >> 6;      // wave 0..7 = column panel
  const int l31 = ln & 31;
  const int lh  = ln >> 5;
  const int cb  = wv * 32;

  // fragment-ordered weight streams: 1KB contiguous per (mat, k)
  const u16* wA1 = Wf + 0 * 65536 + (wv * 16) * 512 + ln * 8;
  const u16* wA2 = Wf + 1 * 65536 + (wv * 16) * 512 + ln * 8;
  const u16* wW1 = Wf + 2 * 65536 + (wv * 16) * 512 + ln * 8;
  const u16* wW2 = Wf + 3 * 65536 + (wv * 16) * 512 + ln * 8;

  // ---- pass 1: gate scores ----
  {
    f32x16 G0, G1;
#pragma unroll
    for (int i = 0; i < 16; i++) { G0[i] = 0.f; G1[i] = 0.f; }

#pragma unroll 4
    for (int k = 0; k < 16; k++) {
      bf16x8 af0 = *(const bf16x8*)(&lX0[l31][k * 16 + lh * 8]);
      bf16x8 af1 = *(const bf16x8*)(&lX1[l31][k * 16 + lh * 8]);
      G0 = __builtin_amdgcn_mfma_f32_32x32x16_bf16(
          af0, *(const bf16x8*)(wA1 + k * 512), G0, 0, 0, 0);
      G1 = __builtin_amdgcn_mfma_f32_32x32x16_bf16(
          af1, *(const bf16x8*)(wA2 + k * 512), G1, 0, 0, 0);
    }

    float v[16];
#pragma unroll
    for (int r = 0; r < 16; r++) {   // gate0: Z0 = X0@A1^T, other = X1
      const int row = (r & 3) + 8 * (r >> 2) + 4 * lh;
      v[r] = G0[r] * b2f(lX1[row][cb + l31]);
    }
    reduce_accum(v, sp0, l31, lh);
#pragma unroll
    for (int r = 0; r < 16; r++) {   // gate1: Z1 = X1@A2^T, other = X0
      const int row = (r & 3) + 8 * (r >> 2) + 4 * lh;
      v[r] = G1[r] * b2f(lX0[row][cb + l31]);
    }
    reduce_accum(v, sp1, l31, lh);
  }
  __syncthreads();

  if (t < BM) {
    sc0[t] = 1.f + 1.f / (1.f + __expf(-sp0[t]));
  } else if (t < 2 * BM) {
    sc1[t - BM] = 1.f + 1.f / (1.f + __expf(-sp1[t - BM]));
  }
  __syncthreads();

  // ---- pass 2: projections, gate-scale in epilogue ----
  {
    f32x16 P0, P1;
#pragma unroll
    for (int i = 0; i < 16; i++) { P0[i] = 0.f; P1[i] = 0.f; }

#pragma unroll 4
    for (int k = 0; k < 16; k++) {
      bf16x8 af0 = *(const bf16x8*)(&lX0[l31][k * 16 + lh * 8]);
      bf16x8 af1 = *(const bf16x8*)(&lX1[l31][k * 16 + lh * 8]);
      P0 = __builtin_amdgcn_mfma_f32_32x32x16_bf16(
          af0, *(const bf16x8*)(wW1 + k * 512), P0, 0, 0, 0);
      P1 = __builtin_amdgcn_mfma_f32_32x32x16_bf16(
          af1, *(const bf16x8*)(wW2 + k * 512), P1, 0, 0, 0);
    }

    float* opb = outg + (size_t)row0 * 256 + cb;
#pragma unroll
    for (int q = 0; q < 4; q++) {
      float s0a[4], s1a[4];
      *(float4*)s0a = *(const float4*)&sc0[8 * q + 4 * lh];
      *(float4*)s1a = *(const float4*)&sc1[8 * q + 4 * lh];
#pragma unroll
      for (int j = 0; j < 4; j++) {
        const int r = q * 4 + j;
        const int row = j + 8 * q + 4 * lh;
        __builtin_nontemporal_store(s0a[j] * P0[r] + s1a[j] * P1[r],
                                    &opb[row * 256 + l31]);
      }
    }
  }
}

extern "C" void kernel_launch(void* const* d_in, const int* in_sizes, int n_in,
                              void* d_out, int out_size, void* d_ws, size_t ws_size,
                              hipStream_t stream) {
  const float* i0 = (const float*)d_in[0];
  const float* i1 = (const float*)d_in[1];
  const float* W1 = (const float*)d_in[2];
  const float* W2 = (const float*)d_in[3];
  const float* a1 = (const float*)d_in[4];
  const float* a2 = (const float*)d_in[5];
  u16* Wf = (u16*)d_ws;   // 4 x 256x256 bf16 = 512 KB, fragment-ordered

  build_wfrag<<<dim3(32, 4), 256, 0, stream>>>(a1, a2, W1, W2, Wf);
  fused<<<NBLK, NT, 0, stream>>>(i0, i1, Wf, (float*)d_out);
}